// Round 1
// baseline (3080.941 us; speedup 1.0000x reference)
//
#include <hip/hip_runtime.h>
#include <cmath>

typedef unsigned char u8;

#define B 256
#define F 128
#define Q 4096
#define E 128
#define INV_TAU 5.0f

// ---- ws layout (offsets in floats) ----
#define W_TNORM   0u            // E*B*F = 4194304
#define W_INVN    4194304u      // E*Q   = 524288
#define W_SCORES  4718592u      // B*Q   = 1048576
#define W_CNT     5767168u      // B*Q   = 1048576
#define W_UNC     6815744u      // Q     = 4096
#define W_NLSE    6819840u      // B
#define W_MOCO    6820096u      // B
#define W_EASY    6820352u      // B
#define W_HARD    6820608u      // B
#define W_UB      6820864u      // 1
#define W_SIM     6820928u      // chunk * B*Q

// ---- out layout (floats) ----
#define O_MOCO   0u
#define O_LOGITS 1u            // (B, Q+1)
#define O_ELOSS  1048833u
#define O_EMASK  1048834u      // (B, Q)
#define O_HLOSS  2097410u
#define O_HMASK  2097411u      // (B, Q)

__global__ void k_zero(float* __restrict__ p) {
    p[(size_t)blockIdx.x * 256 + threadIdx.x] = 0.f;
}

// one block (128 thr) per (e,b) row: masked l2-normalize teacher row
__global__ void k_tnorm(const float* __restrict__ teacher, const u8* __restrict__ mask_t,
                        float* __restrict__ tnorm) {
    int eb = blockIdx.x;          // e*B + b
    int b  = eb & (B - 1);
    int f  = threadIdx.x;
    float v = mask_t[(size_t)eb * F + f] ? 0.f : teacher[b * F + f];
    float ss = v * v;
    #pragma unroll
    for (int o = 32; o > 0; o >>= 1) ss += __shfl_down(ss, o);
    __shared__ float s2[2];
    if ((threadIdx.x & 63) == 0) s2[threadIdx.x >> 6] = ss;
    __syncthreads();
    float d = fmaxf(sqrtf(s2[0] + s2[1]), 1e-12f);
    tnorm[(size_t)eb * F + f] = v / d;
}

// per (e,q): 1/(TAU * ||masked neg column||)
__global__ void k_invn(const float* __restrict__ neg, const u8* __restrict__ mask_n,
                       float* __restrict__ invn) {
    int e = blockIdx.x;
    int q = blockIdx.y * 256 + threadIdx.x;
    float ss = 0.f;
    #pragma unroll 4
    for (int f = 0; f < F; f++) {
        float v = mask_n[((size_t)e * F + f) * Q + q] ? 0.f : neg[f * Q + q];
        ss += v * v;
    }
    invn[e * Q + q] = INV_TAU / fmaxf(sqrtf(ss), 1e-12f);
}

// block per b: logits row (pos + neg) scaled by 1/TAU, written to out
__global__ void k_logits(const float* __restrict__ query, const float* __restrict__ key,
                         const float* __restrict__ neg, float* __restrict__ out) {
    __shared__ float qrow[F];
    __shared__ float red[256];
    int b = blockIdx.x, t = threadIdx.x;
    float pp = 0.f;
    if (t < F) { float qv = query[b * F + t]; qrow[t] = qv; pp = qv * key[b * F + t]; }
    red[t] = pp;
    __syncthreads();
    for (int s = 128; s > 0; s >>= 1) { if (t < s) red[t] += red[t + s]; __syncthreads(); }
    float pos = red[0];
    float acc[16];
    #pragma unroll
    for (int j = 0; j < 16; j++) acc[j] = 0.f;
    for (int f = 0; f < F; f++) {
        float a = qrow[f];
        const float* np_ = neg + (size_t)f * Q + t;
        #pragma unroll
        for (int j = 0; j < 16; j++) acc[j] = fmaf(a, np_[256 * j], acc[j]);
    }
    float* row = out + O_LOGITS + (size_t)b * (Q + 1);
    #pragma unroll
    for (int j = 0; j < 16; j++) row[1 + t + 256 * j] = acc[j] * INV_TAU;
    if (t == 0) row[0] = pos * INV_TAU;
}

// block per b: moco part (full-row LSE - z0) and neg-only LSE for later losses
__global__ void k_rowstats(const float* __restrict__ out, float* __restrict__ moco_part,
                           float* __restrict__ nlse) {
    __shared__ float red[256];
    int b = blockIdx.x, t = threadIdx.x;
    const float* row = out + O_LOGITS + (size_t)b * (Q + 1);
    float m = -INFINITY, mn = -INFINITY;
    for (int j = 0; j < 17; j++) {
        int i = t + 256 * j;
        if (i < Q + 1) { float z = row[i]; m = fmaxf(m, z); if (i >= 1) mn = fmaxf(mn, z); }
    }
    red[t] = m; __syncthreads();
    for (int s = 128; s > 0; s >>= 1) { if (t < s) red[t] = fmaxf(red[t], red[t + s]); __syncthreads(); }
    float M = red[0]; __syncthreads();
    red[t] = mn; __syncthreads();
    for (int s = 128; s > 0; s >>= 1) { if (t < s) red[t] = fmaxf(red[t], red[t + s]); __syncthreads(); }
    float Mn = red[0]; __syncthreads();
    float s1 = 0.f, s2 = 0.f;
    for (int j = 0; j < 17; j++) {
        int i = t + 256 * j;
        if (i < Q + 1) { float z = row[i]; s1 += expf(z - M); if (i >= 1) s2 += expf(z - Mn); }
    }
    red[t] = s1; __syncthreads();
    for (int s = 128; s > 0; s >>= 1) { if (t < s) red[t] += red[t + s]; __syncthreads(); }
    float S = red[0]; __syncthreads();
    red[t] = s2; __syncthreads();
    for (int s = 128; s > 0; s >>= 1) { if (t < s) red[t] += red[t + s]; __syncthreads(); }
    float Sn = red[0];
    if (t == 0) { moco_part[b] = M + logf(S) - row[0]; nlse[b] = Mn + logf(Sn); }
}

// sim[el,b,q] = tnorm[e,b,:] . (masked neg col * invn)  — fp32 tiled GEMM, 64x64 tile, K split 2x64
__global__ void __launch_bounds__(256) k_gemm(const float* __restrict__ tnorm,
                                              const float* __restrict__ neg,
                                              const u8* __restrict__ mask_n,
                                              const float* __restrict__ invn,
                                              float* __restrict__ sim, int e0) {
    __shared__ float At[64][65];                    // [k][row], +1 pad
    __shared__ __align__(16) float Bs[64][64];      // [k][qq]
    int el = blockIdx.z, e = e0 + el;
    int q0 = blockIdx.x * 64, b0 = blockIdx.y * 64;
    int tid = threadIdx.x;
    int tx = tid & 15, ty = tid >> 4;
    float acc[4][4];
    #pragma unroll
    for (int i = 0; i < 4; i++)
        #pragma unroll
        for (int j = 0; j < 4; j++) acc[i][j] = 0.f;

    for (int kb = 0; kb < 2; kb++) {
        #pragma unroll
        for (int i = 0; i < 16; i++) {
            int l = tid + 256 * i;
            int row = l >> 6, kk = l & 63;
            At[kk][row] = tnorm[((size_t)(e * B + b0 + row)) * F + kb * 64 + kk];
        }
        #pragma unroll
        for (int i = 0; i < 16; i++) {
            int l = tid + 256 * i;
            int kk = l >> 6, qq = l & 63;
            int q = q0 + qq;
            u8 mm = mask_n[((size_t)e * F + kb * 64 + kk) * Q + q];
            Bs[kk][qq] = mm ? 0.f : neg[(kb * 64 + kk) * Q + q] * invn[e * Q + q];
        }
        __syncthreads();
        #pragma unroll 4
        for (int k = 0; k < 64; k++) {
            float a0 = At[k][ty * 4 + 0];
            float a1 = At[k][ty * 4 + 1];
            float a2 = At[k][ty * 4 + 2];
            float a3 = At[k][ty * 4 + 3];
            float4 bv = *(const float4*)&Bs[k][tx * 4];
            acc[0][0] = fmaf(a0, bv.x, acc[0][0]); acc[0][1] = fmaf(a0, bv.y, acc[0][1]);
            acc[0][2] = fmaf(a0, bv.z, acc[0][2]); acc[0][3] = fmaf(a0, bv.w, acc[0][3]);
            acc[1][0] = fmaf(a1, bv.x, acc[1][0]); acc[1][1] = fmaf(a1, bv.y, acc[1][1]);
            acc[1][2] = fmaf(a1, bv.z, acc[1][2]); acc[1][3] = fmaf(a1, bv.w, acc[1][3]);
            acc[2][0] = fmaf(a2, bv.x, acc[2][0]); acc[2][1] = fmaf(a2, bv.y, acc[2][1]);
            acc[2][2] = fmaf(a2, bv.z, acc[2][2]); acc[2][3] = fmaf(a2, bv.w, acc[2][3]);
            acc[3][0] = fmaf(a3, bv.x, acc[3][0]); acc[3][1] = fmaf(a3, bv.y, acc[3][1]);
            acc[3][2] = fmaf(a3, bv.z, acc[3][2]); acc[3][3] = fmaf(a3, bv.w, acc[3][3]);
        }
        __syncthreads();
    }
    #pragma unroll
    for (int i = 0; i < 4; i++) {
        int r = b0 + ty * 4 + i;
        float4 v = make_float4(acc[i][0], acc[i][1], acc[i][2], acc[i][3]);
        *(float4*)&sim[((size_t)el * B + r) * Q + q0 + tx * 4] = v;
    }
}

// masked softmax over B (boot_mask) -> entropy -> atomicAdd into unc_acc[q]
__global__ void k_entropy(const float* __restrict__ sim, const u8* __restrict__ boot,
                          float* __restrict__ unc_acc, int e0) {
    __shared__ float sm[4][64], ssum[4][64], sent[4][64];
    __shared__ int scnt[4][64];
    int el = blockIdx.y, e = e0 + el;
    int tq = threadIdx.x & 63, seg = threadIdx.x >> 6;
    int q = blockIdx.x * 64 + tq;
    const float* sc = sim + (size_t)el * B * Q + q;
    const u8* bm = boot + (size_t)e * B * Q + q;
    float m = -INFINITY, s = 0.f; int cnt = 0;
    #pragma unroll 4
    for (int bi = 0; bi < 64; bi++) {
        int bb = seg * 64 + bi;
        float z = sc[(size_t)bb * Q];
        if (bm[(size_t)bb * Q]) {
            cnt++;
            if (z > m) { s = s * expf(m - z) + 1.f; m = z; }
            else        s += expf(z - m);
        }
    }
    sm[seg][tq] = m; ssum[seg][tq] = s; scnt[seg][tq] = cnt;
    __syncthreads();
    float M = fmaxf(fmaxf(sm[0][tq], sm[1][tq]), fmaxf(sm[2][tq], sm[3][tq]));
    int C = scnt[0][tq] + scnt[1][tq] + scnt[2][tq] + scnt[3][tq];
    float S = 0.f;
    #pragma unroll
    for (int i = 0; i < 4; i++) {
        float mi = sm[i][tq];
        if (mi != -INFINITY) S += ssum[i][tq] * expf(mi - M);
    }
    if (M == -INFINITY) M = 0.f;        // ref guard for fully-masked column
    float Sc = fmaxf(S, 1e-30f);
    float ent = 0.f;
    #pragma unroll 4
    for (int bi = 0; bi < 64; bi++) {
        int bb = seg * 64 + bi;
        float z = sc[(size_t)bb * Q];
        float p = bm[(size_t)bb * Q] ? expf(z - M) / Sc : 0.f;
        p += 1e-7f;
        ent -= p * logf(p);
    }
    sent[seg][tq] = ent;
    __syncthreads();
    if (seg == 0) {
        float tot = sent[0][tq] + sent[1][tq] + sent[2][tq] + sent[3][tq];
        atomicAdd(&unc_acc[q], tot / fmaxf((float)C, 1.f));
    }
}

// masked softmax over Q (score_mask), overwrite sim row with probs
__global__ void k_probs(float* __restrict__ sim, const u8* __restrict__ smask, int e0) {
    __shared__ float red[256];
    int el = blockIdx.y, e = e0 + el, b = blockIdx.x, t = threadIdx.x;
    float* row = sim + ((size_t)el * B + b) * Q;
    const u8* mk = smask + ((size_t)e * B + b) * Q;
    float z[16]; u8 mm[16];
    float lm = -INFINITY;
    #pragma unroll
    for (int j = 0; j < 16; j++) {
        int q = t + 256 * j;
        z[j] = row[q]; mm[j] = mk[q];
        if (mm[j]) lm = fmaxf(lm, z[j]);
    }
    red[t] = lm; __syncthreads();
    for (int s = 128; s > 0; s >>= 1) { if (t < s) red[t] = fmaxf(red[t], red[t + s]); __syncthreads(); }
    float M = red[0]; __syncthreads();
    if (M == -INFINITY) M = 0.f;
    float ls = 0.f; float ev[16];
    #pragma unroll
    for (int j = 0; j < 16; j++) { ev[j] = mm[j] ? expf(z[j] - M) : 0.f; ls += ev[j]; }
    red[t] = ls; __syncthreads();
    for (int s = 128; s > 0; s >>= 1) { if (t < s) red[t] += red[t + s]; __syncthreads(); }
    float Sc = fmaxf(red[0], 1e-30f);
    #pragma unroll
    for (int j = 0; j < 16; j++) row[t + 256 * j] = ev[j] / Sc;
}

// scores_acc += sum_el probs ; cnt_acc += sum_el score_mask
__global__ void k_accum(const float* __restrict__ sim, const u8* __restrict__ smask,
                        float* __restrict__ sacc, float* __restrict__ cacc, int e0, int ecnt) {
    int idx = blockIdx.x * 256 + threadIdx.x;
    float s = 0.f, c = 0.f;
    for (int el = 0; el < ecnt; el++) {
        s += sim[(size_t)el * B * Q + idx];
        c += (float)smask[((size_t)(e0 + el)) * B * Q + idx];
    }
    sacc[idx] += s; cacc[idx] += c;
}

__global__ void k_finscores(float* __restrict__ sacc, const float* __restrict__ cacc) {
    int idx = blockIdx.x * 256 + threadIdx.x;
    sacc[idx] = sacc[idx] / fmaxf(cacc[idx], 1.f);
}

// normalize unc (/E), bitonic sort 4096, median per np.quantile 'linear'
__global__ void k_median(float* __restrict__ unc, float* __restrict__ ubp) {
    __shared__ float sd[4096];
    int t = threadIdx.x;
    #pragma unroll
    for (int j = 0; j < 4; j++) {
        int q = t + 1024 * j;
        float u = unc[q] * (1.f / 128.f);
        unc[q] = u; sd[q] = u;
    }
    __syncthreads();
    for (int k = 2; k <= 4096; k <<= 1) {
        for (int j = k >> 1; j > 0; j >>= 1) {
            #pragma unroll
            for (int base = 0; base < 4; base++) {
                int i = t + 1024 * base;
                int ixj = i ^ j;
                if (ixj > i) {
                    bool up = ((i & k) == 0);
                    float x = sd[i], y = sd[ixj];
                    if ((x > y) == up) { sd[i] = y; sd[ixj] = x; }
                }
            }
            __syncthreads();
        }
    }
    if (t == 0) { float a = sd[2047], b2 = sd[2048]; ubp[0] = a + 0.5f * (b2 - a); }
}

// per (b, mode): argmax of scores among allowed q (lowest-index ties), mask + loss part
__global__ void k_select(float* __restrict__ out, const float* __restrict__ scores,
                         const float* __restrict__ unc, const float* __restrict__ ubp,
                         const float* __restrict__ nlse, float* __restrict__ easy_part,
                         float* __restrict__ hard_part) {
    __shared__ float rv[256];
    __shared__ int ri[256];
    __shared__ int bshare;
    int b = blockIdx.x, mode = blockIdx.y, t = threadIdx.x;
    float ub = ubp[0];
    float bv = -INFINITY; int bidx = Q;
    #pragma unroll
    for (int j = 0; j < 16; j++) {
        int q = t + 256 * j;
        float u = unc[q];
        bool ok = (mode == 0) ? (u <= ub) : (u >= ub);
        if (ok) {
            float v = scores[(size_t)b * Q + q];
            if (v > bv || (v == bv && q < bidx)) { bv = v; bidx = q; }
        }
    }
    rv[t] = bv; ri[t] = bidx; __syncthreads();
    for (int s = 128; s > 0; s >>= 1) {
        if (t < s) {
            float v2 = rv[t + s]; int i2 = ri[t + s];
            if (v2 > rv[t] || (v2 == rv[t] && i2 < ri[t])) { rv[t] = v2; ri[t] = i2; }
        }
        __syncthreads();
    }
    if (t == 0) {
        int best = ri[0]; bshare = best;
        float z = out[O_LOGITS + (size_t)b * (Q + 1) + 1 + best];
        float loss = nlse[b] - z;                 // -log_softmax_neg at best
        (mode == 0 ? easy_part : hard_part)[b] = loss;
    }
    __syncthreads();
    int best = bshare;
    float* mrow = out + (mode == 0 ? O_EMASK : O_HMASK) + (size_t)b * Q;
    #pragma unroll
    for (int j = 0; j < 16; j++) { int q = t + 256 * j; mrow[q] = (q == best) ? 1.f : 0.f; }
}

__global__ void k_scalars(const float* __restrict__ moco, const float* __restrict__ easyp,
                          const float* __restrict__ hardp, float* __restrict__ out) {
    __shared__ float red[256];
    int t = threadIdx.x;
    red[t] = moco[t]; __syncthreads();
    for (int s = 128; s > 0; s >>= 1) { if (t < s) red[t] += red[t + s]; __syncthreads(); }
    if (t == 0) out[O_MOCO] = red[0] / 256.f;
    __syncthreads();
    red[t] = easyp[t]; __syncthreads();
    for (int s = 128; s > 0; s >>= 1) { if (t < s) red[t] += red[t + s]; __syncthreads(); }
    if (t == 0) out[O_ELOSS] = red[0] / 256.f;
    __syncthreads();
    red[t] = hardp[t]; __syncthreads();
    for (int s = 128; s > 0; s >>= 1) { if (t < s) red[t] += red[t + s]; __syncthreads(); }
    if (t == 0) out[O_HLOSS] = red[0] / 256.f;
}

extern "C" void kernel_launch(void* const* d_in, const int* in_sizes, int n_in,
                              void* d_out, int out_size, void* d_ws, size_t ws_size,
                              hipStream_t stream) {
    const float* query   = (const float*)d_in[0];
    const float* key     = (const float*)d_in[1];
    const float* teacher = (const float*)d_in[2];
    const float* neg     = (const float*)d_in[3];
    const u8* mask_t     = (const u8*)d_in[4];
    const u8* mask_n     = (const u8*)d_in[5];
    const u8* score_mask = (const u8*)d_in[6];
    const u8* boot_mask  = (const u8*)d_in[7];
    float* out = (float*)d_out;
    float* ws  = (float*)d_ws;

    long ws_floats = (long)(ws_size / 4);
    long avail = ws_floats - (long)W_SIM;
    int chunk = (int)(avail / ((long)B * Q));
    if (chunk > 16) chunk = 16;
    if (chunk < 1) chunk = 1;

    // zero scores_acc + cnt_acc + unc_acc (contiguous 2101248 floats)
    k_zero<<<2101248 / 256, 256, 0, stream>>>(ws + W_SCORES);
    k_tnorm<<<E * B, 128, 0, stream>>>(teacher, mask_t, ws + W_TNORM);
    k_invn<<<dim3(E, Q / 256), 256, 0, stream>>>(neg, mask_n, ws + W_INVN);
    k_logits<<<B, 256, 0, stream>>>(query, key, neg, out);
    k_rowstats<<<B, 256, 0, stream>>>(out, ws + W_MOCO, ws + W_NLSE);

    for (int e0 = 0; e0 < E; e0 += chunk) {
        int ecnt = (E - e0 < chunk) ? (E - e0) : chunk;
        k_gemm<<<dim3(Q / 64, B / 64, ecnt), 256, 0, stream>>>(
            ws + W_TNORM, neg, mask_n, ws + W_INVN, ws + W_SIM, e0);
        k_entropy<<<dim3(Q / 64, ecnt), 256, 0, stream>>>(
            ws + W_SIM, boot_mask, ws + W_UNC, e0);
        k_probs<<<dim3(B, ecnt), 256, 0, stream>>>(ws + W_SIM, score_mask, e0);
        k_accum<<<(B * Q) / 256, 256, 0, stream>>>(
            ws + W_SIM, score_mask, ws + W_SCORES, ws + W_CNT, e0, ecnt);
    }

    k_finscores<<<(B * Q) / 256, 256, 0, stream>>>(ws + W_SCORES, ws + W_CNT);
    k_median<<<1, 1024, 0, stream>>>(ws + W_UNC, ws + W_UB);
    k_select<<<dim3(B, 2), 256, 0, stream>>>(out, ws + W_SCORES, ws + W_UNC, ws + W_UB,
                                             ws + W_NLSE, ws + W_EASY, ws + W_HARD);
    k_scalars<<<1, 256, 0, stream>>>(ws + W_MOCO, ws + W_EASY, ws + W_HARD, out);
}

// Round 2
// 1989.058 us; speedup vs baseline: 1.5489x; 1.5489x over previous
//
#include <hip/hip_runtime.h>
#include <cmath>

typedef unsigned char u8;
typedef unsigned short u16;
typedef __attribute__((ext_vector_type(8))) short s8v;    // 8 bf16 = 4 VGPRs
typedef __attribute__((ext_vector_type(4))) float f32x4;  // MFMA acc

#define B 256
#define F 128
#define Q 4096
#define E 128
#define INV_TAU 5.0f

// ---- ws layout (offsets in floats) ----
#define W_SCORES 0u            // B*Q = 1048576
#define W_CNT    1048576u      // B*Q
#define W_UNC    2097152u      // 4096
#define W_NLSE   2101248u      // 256
#define W_MOCO   2101504u      // 256
#define W_EASY   2101760u      // 256
#define W_HARD   2102016u      // 256
#define W_UB     2102272u      // 1 (padded)
#define W_MROW   2102528u      // chunk*B <= 4096
#define W_SROW   2106624u      // chunk*B <= 4096
#define W_INVN   2110720u      // E*Q = 524288
#define W_AF     2635008u      // bf16 E*B*F -> 2097152 floats
#define W_BF     4732160u      // bf16 chunk*F*Q -> up to 4194304 floats
// W_SIM computed at runtime: W_BF + chunk*F*Q/2

// ---- out layout (floats) ----
#define O_MOCO   0u
#define O_LOGITS 1u            // (B, Q+1)
#define O_ELOSS  1048833u
#define O_EMASK  1048834u      // (B, Q)
#define O_HLOSS  2097410u
#define O_HMASK  2097411u      // (B, Q)

static __device__ __forceinline__ u16 f2bf(float x) {
    unsigned int u = __builtin_bit_cast(unsigned int, x);
    unsigned int r = (u + 0x7FFFu + ((u >> 16) & 1u)) >> 16;
    return (u16)r;
}

__global__ void k_zero(float* __restrict__ p) {
    p[(size_t)blockIdx.x * 256 + threadIdx.x] = 0.f;
}

// one block (128 thr) per (e,b): masked l2-norm of teacher row -> bf16 A-fragments
// A-frag layout: elem offset (((e*16+bg)*4+kb)*64 + lane)*8 + j
//   bg=b>>4, m=b&15, kb=f>>5, quad=(f>>3)&3, j=f&7, lane=quad*16+m
__global__ void k_afrag(const float* __restrict__ teacher, const u8* __restrict__ mask_t,
                        u16* __restrict__ af) {
    int eb = blockIdx.x;          // e*B + b
    int e  = eb >> 8;
    int b  = eb & (B - 1);
    int f  = threadIdx.x;
    float v = mask_t[(size_t)eb * F + f] ? 0.f : teacher[b * F + f];
    float ss = v * v;
    #pragma unroll
    for (int o = 32; o > 0; o >>= 1) ss += __shfl_down(ss, o);
    __shared__ float s2[2];
    if ((threadIdx.x & 63) == 0) s2[threadIdx.x >> 6] = ss;
    __syncthreads();
    float d = fmaxf(sqrtf(s2[0] + s2[1]), 1e-12f);
    float t = v / d;
    int bg = b >> 4, m = b & 15;
    int kb = f >> 5, quad = (f >> 3) & 3, j = f & 7;
    int lane = quad * 16 + m;
    af[((((size_t)e * 16 + bg) * 4 + kb) * 64 + lane) * 8 + j] = f2bf(t);
}

// per (e,q): 1/(TAU * ||masked neg column||)
__global__ void k_invn(const float* __restrict__ neg, const u8* __restrict__ mask_n,
                       float* __restrict__ invn) {
    int e = blockIdx.x;
    int q = blockIdx.y * 256 + threadIdx.x;
    float ss = 0.f;
    #pragma unroll 4
    for (int f = 0; f < F; f++) {
        float v = mask_n[((size_t)e * F + f) * Q + q] ? 0.f : neg[f * Q + q];
        ss += v * v;
    }
    invn[e * Q + q] = INV_TAU / fmaxf(sqrtf(ss), 1e-12f);
}

// per chunk: masked-normalized negatives -> bf16 B-fragments
// B-frag layout: frag idx ((el*256+qg)*4+kb)*64 + lane ; within: j=0..7
//   q = qg*16 + (lane&15), f = kb*32 + (lane>>4)*8 + j
__global__ void k_bfrag(const float* __restrict__ neg, const u8* __restrict__ mask_n,
                        const float* __restrict__ invn, u16* __restrict__ bf, int e0) {
    int el = blockIdx.y, e = e0 + el;
    int t = blockIdx.x * 256 + threadIdx.x;       // 0..65535 per e
    int qg = t >> 8;
    int r = t & 255;
    int kb = r >> 6, lane = r & 63;
    int q = (qg << 4) | (lane & 15);
    int fbase = kb * 32 + (lane >> 4) * 8;
    float iv = invn[e * Q + q];
    u16 outv[8];
    #pragma unroll
    for (int j = 0; j < 8; j++) {
        int f = fbase + j;
        u8 mm = mask_n[((size_t)e * F + f) * Q + q];
        float v = mm ? 0.f : neg[(size_t)f * Q + q] * iv;
        outv[j] = f2bf(v);
    }
    *(s8v*)&bf[((((size_t)el * 256 + qg) * 4 + kb) * 64 + lane) * 8] =
        *(const s8v*)outv;
}

// sim[el,b,q] via bf16 MFMA 16x16x32, K=128 -> 4 mfma per tile
__global__ void __launch_bounds__(256) k_mfma(const u16* __restrict__ af,
                                              const u16* __restrict__ bf,
                                              float* __restrict__ sim, int e0) {
    int el = blockIdx.z, e = e0 + el;
    int bg = blockIdx.y;
    int wave = threadIdx.x >> 6, lane = threadIdx.x & 63;
    int qg0 = blockIdx.x * 16 + wave * 4;         // 4 q-tiles per wave
    const s8v* A = (const s8v*)af + ((size_t)(e * 16 + bg) * 4) * 64;
    const s8v* Bf = (const s8v*)bf;
    s8v a[4];
    #pragma unroll
    for (int kb = 0; kb < 4; kb++) a[kb] = A[kb * 64 + lane];
    int r0 = bg * 16 + (lane >> 4) * 4;
    int colb = lane & 15;
    #pragma unroll
    for (int qt = 0; qt < 4; qt++) {
        int qg = qg0 + qt;
        f32x4 acc = {0.f, 0.f, 0.f, 0.f};
        #pragma unroll
        for (int kb = 0; kb < 4; kb++) {
            s8v bv = Bf[((size_t)(el * 256 + qg) * 4 + kb) * 64 + lane];
            acc = __builtin_amdgcn_mfma_f32_16x16x32_bf16(a[kb], bv, acc, 0, 0, 0);
        }
        int col = qg * 16 + colb;
        #pragma unroll
        for (int r = 0; r < 4; r++)
            sim[((size_t)el * B + r0 + r) * Q + col] = acc[r];
    }
}

// masked softmax over B (boot_mask) -> entropy -> atomicAdd into unc_acc[q]
// single global pass: 64 column values cached in registers per thread
__global__ void k_entropy(const float* __restrict__ sim, const u8* __restrict__ boot,
                          float* __restrict__ unc_acc, int e0) {
    __shared__ float sm[4][64], ssum[4][64], sent[4][64];
    __shared__ int scnt[4][64];
    int el = blockIdx.y, e = e0 + el;
    int tq = threadIdx.x & 63, seg = threadIdx.x >> 6;
    int q = blockIdx.x * 64 + tq;
    const float* sc = sim + ((size_t)el * B + seg * 64) * Q + q;
    const u8* bm = boot + ((size_t)e * B + seg * 64) * Q + q;
    float z[64];
    unsigned long long mk = 0ull;
    float m = -INFINITY;
    #pragma unroll
    for (int bi = 0; bi < 64; bi++) {
        z[bi] = sc[(size_t)bi * Q];
        if (bm[(size_t)bi * Q]) { mk |= 1ull << bi; m = fmaxf(m, z[bi]); }
    }
    float s = 0.f;
    #pragma unroll
    for (int bi = 0; bi < 64; bi++)
        if ((mk >> bi) & 1) s += expf(z[bi] - m);
    sm[seg][tq] = m; ssum[seg][tq] = s; scnt[seg][tq] = __popcll(mk);
    __syncthreads();
    float M = fmaxf(fmaxf(sm[0][tq], sm[1][tq]), fmaxf(sm[2][tq], sm[3][tq]));
    int C = scnt[0][tq] + scnt[1][tq] + scnt[2][tq] + scnt[3][tq];
    float S = 0.f;
    #pragma unroll
    for (int i = 0; i < 4; i++) {
        float mi = sm[i][tq];
        if (mi != -INFINITY) S += ssum[i][tq] * expf(mi - M);
    }
    if (M == -INFINITY) M = 0.f;          // ref guard for fully-masked column
    float invS = 1.f / fmaxf(S, 1e-30f);
    const float P0 = 1e-7f;
    float C0 = -(P0 * logf(P0));          // masked-entry entropy contribution
    float ent = 0.f;
    #pragma unroll
    for (int bi = 0; bi < 64; bi++) {
        if ((mk >> bi) & 1) {
            float p = expf(z[bi] - M) * invS + P0;
            ent -= p * logf(p);
        } else {
            ent += C0;
        }
    }
    sent[seg][tq] = ent;
    __syncthreads();
    if (seg == 0) {
        float tot = sent[0][tq] + sent[1][tq] + sent[2][tq] + sent[3][tq];
        atomicAdd(&unc_acc[q], tot / fmaxf((float)C, 1.f));
    }
}

// per (el,b) row: masked max + masked exp-sum over Q (score_mask) -> guarded M, Sc
__global__ void k_rowmax(const float* __restrict__ sim, const u8* __restrict__ smask,
                         float* __restrict__ mrow, float* __restrict__ srow, int e0) {
    __shared__ float red[256];
    int b = blockIdx.x, el = blockIdx.y, e = e0 + el, t = threadIdx.x;
    const float* row = sim + ((size_t)el * B + b) * Q;
    const u8* mk = smask + ((size_t)e * B + b) * Q;
    float z[16]; u8 mm[16];
    float lm = -INFINITY;
    #pragma unroll
    for (int j = 0; j < 16; j++) {
        int qq = t + 256 * j;
        z[j] = row[qq]; mm[j] = mk[qq];
        if (mm[j]) lm = fmaxf(lm, z[j]);
    }
    red[t] = lm; __syncthreads();
    for (int s = 128; s > 0; s >>= 1) { if (t < s) red[t] = fmaxf(red[t], red[t + s]); __syncthreads(); }
    float M = red[0]; __syncthreads();
    if (M == -INFINITY) M = 0.f;
    float ls = 0.f;
    #pragma unroll
    for (int j = 0; j < 16; j++) if (mm[j]) ls += expf(z[j] - M);
    red[t] = ls; __syncthreads();
    for (int s = 128; s > 0; s >>= 1) { if (t < s) red[t] += red[t + s]; __syncthreads(); }
    if (t == 0) { mrow[el * B + b] = M; srow[el * B + b] = fmaxf(red[0], 1e-30f); }
}

// scores_acc += sum_el exp(z-M)/Sc (masked) ; cnt_acc += sum_el score_mask
__global__ void k_accum(const float* __restrict__ sim, const u8* __restrict__ smask,
                        const float* __restrict__ mrow, const float* __restrict__ srow,
                        float* __restrict__ sacc, float* __restrict__ cacc, int e0, int ecnt) {
    int idx = blockIdx.x * 256 + threadIdx.x;
    int b = idx >> 12;
    float s = 0.f, c = 0.f;
    for (int el = 0; el < ecnt; el++) {
        float z = sim[(size_t)el * B * Q + idx];
        u8 a = smask[((size_t)(e0 + el) * B) * Q + idx];
        float M = mrow[el * B + b];
        float iS = 1.f / srow[el * B + b];
        if (a) { s += expf(z - M) * iS; c += 1.f; }
    }
    sacc[idx] += s; cacc[idx] += c;
}

__global__ void k_finscores(float* __restrict__ sacc, const float* __restrict__ cacc) {
    int idx = blockIdx.x * 256 + threadIdx.x;
    sacc[idx] = sacc[idx] / fmaxf(cacc[idx], 1.f);
}

// block per b: logits row (pos + neg) scaled by 1/TAU, written to out
__global__ void k_logits(const float* __restrict__ query, const float* __restrict__ key,
                         const float* __restrict__ neg, float* __restrict__ out) {
    __shared__ float qrow[F];
    __shared__ float red[256];
    int b = blockIdx.x, t = threadIdx.x;
    float pp = 0.f;
    if (t < F) { float qv = query[b * F + t]; qrow[t] = qv; pp = qv * key[b * F + t]; }
    red[t] = pp;
    __syncthreads();
    for (int s = 128; s > 0; s >>= 1) { if (t < s) red[t] += red[t + s]; __syncthreads(); }
    float pos = red[0];
    float acc[16];
    #pragma unroll
    for (int j = 0; j < 16; j++) acc[j] = 0.f;
    for (int f = 0; f < F; f++) {
        float a = qrow[f];
        const float* np_ = neg + (size_t)f * Q + t;
        #pragma unroll
        for (int j = 0; j < 16; j++) acc[j] = fmaf(a, np_[256 * j], acc[j]);
    }
    float* row = out + O_LOGITS + (size_t)b * (Q + 1);
    #pragma unroll
    for (int j = 0; j < 16; j++) row[1 + t + 256 * j] = acc[j] * INV_TAU;
    if (t == 0) row[0] = pos * INV_TAU;
}

// block per b: moco part (full-row LSE - z0) and neg-only LSE
__global__ void k_rowstats(const float* __restrict__ out, float* __restrict__ moco_part,
                           float* __restrict__ nlse) {
    __shared__ float red[256];
    int b = blockIdx.x, t = threadIdx.x;
    const float* row = out + O_LOGITS + (size_t)b * (Q + 1);
    float m = -INFINITY, mn = -INFINITY;
    for (int j = 0; j < 17; j++) {
        int i = t + 256 * j;
        if (i < Q + 1) { float zz = row[i]; m = fmaxf(m, zz); if (i >= 1) mn = fmaxf(mn, zz); }
    }
    red[t] = m; __syncthreads();
    for (int s = 128; s > 0; s >>= 1) { if (t < s) red[t] = fmaxf(red[t], red[t + s]); __syncthreads(); }
    float M = red[0]; __syncthreads();
    red[t] = mn; __syncthreads();
    for (int s = 128; s > 0; s >>= 1) { if (t < s) red[t] = fmaxf(red[t], red[t + s]); __syncthreads(); }
    float Mn = red[0]; __syncthreads();
    float s1 = 0.f, s2 = 0.f;
    for (int j = 0; j < 17; j++) {
        int i = t + 256 * j;
        if (i < Q + 1) { float zz = row[i]; s1 += expf(zz - M); if (i >= 1) s2 += expf(zz - Mn); }
    }
    red[t] = s1; __syncthreads();
    for (int s = 128; s > 0; s >>= 1) { if (t < s) red[t] += red[t + s]; __syncthreads(); }
    float S = red[0]; __syncthreads();
    red[t] = s2; __syncthreads();
    for (int s = 128; s > 0; s >>= 1) { if (t < s) red[t] += red[t + s]; __syncthreads(); }
    float Sn = red[0];
    if (t == 0) { moco_part[b] = M + logf(S) - row[0]; nlse[b] = Mn + logf(Sn); }
}

// normalize unc (/E), bitonic sort 4096, median per np.quantile 'linear'
__global__ void k_median(float* __restrict__ unc, float* __restrict__ ubp) {
    __shared__ float sd[4096];
    int t = threadIdx.x;
    #pragma unroll
    for (int j = 0; j < 4; j++) {
        int q = t + 1024 * j;
        float u = unc[q] * (1.f / 128.f);
        unc[q] = u; sd[q] = u;
    }
    __syncthreads();
    for (int k = 2; k <= 4096; k <<= 1) {
        for (int j = k >> 1; j > 0; j >>= 1) {
            #pragma unroll
            for (int base = 0; base < 4; base++) {
                int i = t + 1024 * base;
                int ixj = i ^ j;
                if (ixj > i) {
                    bool up = ((i & k) == 0);
                    float x = sd[i], y = sd[ixj];
                    if ((x > y) == up) { sd[i] = y; sd[ixj] = x; }
                }
            }
            __syncthreads();
        }
    }
    if (t == 0) { float a = sd[2047], b2 = sd[2048]; ubp[0] = a + 0.5f * (b2 - a); }
}

// per (b, mode): argmax of scores among allowed q (lowest-index ties), mask + loss part
__global__ void k_select(float* __restrict__ out, const float* __restrict__ scores,
                         const float* __restrict__ unc, const float* __restrict__ ubp,
                         const float* __restrict__ nlse, float* __restrict__ easy_part,
                         float* __restrict__ hard_part) {
    __shared__ float rv[256];
    __shared__ int ri[256];
    __shared__ int bshare;
    int b = blockIdx.x, mode = blockIdx.y, t = threadIdx.x;
    float ub = ubp[0];
    float bv = -INFINITY; int bidx = Q;
    #pragma unroll
    for (int j = 0; j < 16; j++) {
        int q = t + 256 * j;
        float u = unc[q];
        bool ok = (mode == 0) ? (u <= ub) : (u >= ub);
        if (ok) {
            float v = scores[(size_t)b * Q + q];
            if (v > bv || (v == bv && q < bidx)) { bv = v; bidx = q; }
        }
    }
    rv[t] = bv; ri[t] = bidx; __syncthreads();
    for (int s = 128; s > 0; s >>= 1) {
        if (t < s) {
            float v2 = rv[t + s]; int i2 = ri[t + s];
            if (v2 > rv[t] || (v2 == rv[t] && i2 < ri[t])) { rv[t] = v2; ri[t] = i2; }
        }
        __syncthreads();
    }
    if (t == 0) {
        int best = ri[0]; bshare = best;
        float zz = out[O_LOGITS + (size_t)b * (Q + 1) + 1 + best];
        float loss = nlse[b] - zz;
        (mode == 0 ? easy_part : hard_part)[b] = loss;
    }
    __syncthreads();
    int best = bshare;
    float* mrow = out + (mode == 0 ? O_EMASK : O_HMASK) + (size_t)b * Q;
    #pragma unroll
    for (int j = 0; j < 16; j++) { int q = t + 256 * j; mrow[q] = (q == best) ? 1.f : 0.f; }
}

__global__ void k_scalars(const float* __restrict__ moco, const float* __restrict__ easyp,
                          const float* __restrict__ hardp, float* __restrict__ out) {
    __shared__ float red[256];
    int t = threadIdx.x;
    red[t] = moco[t]; __syncthreads();
    for (int s = 128; s > 0; s >>= 1) { if (t < s) red[t] += red[t + s]; __syncthreads(); }
    if (t == 0) out[O_MOCO] = red[0] / 256.f;
    __syncthreads();
    red[t] = easyp[t]; __syncthreads();
    for (int s = 128; s > 0; s >>= 1) { if (t < s) red[t] += red[t + s]; __syncthreads(); }
    if (t == 0) out[O_ELOSS] = red[0] / 256.f;
    __syncthreads();
    red[t] = hardp[t]; __syncthreads();
    for (int s = 128; s > 0; s >>= 1) { if (t < s) red[t] += red[t + s]; __syncthreads(); }
    if (t == 0) out[O_HLOSS] = red[0] / 256.f;
}

extern "C" void kernel_launch(void* const* d_in, const int* in_sizes, int n_in,
                              void* d_out, int out_size, void* d_ws, size_t ws_size,
                              hipStream_t stream) {
    const float* query   = (const float*)d_in[0];
    const float* key     = (const float*)d_in[1];
    const float* teacher = (const float*)d_in[2];
    const float* neg     = (const float*)d_in[3];
    const u8* mask_t     = (const u8*)d_in[4];
    const u8* mask_n     = (const u8*)d_in[5];
    const u8* score_mask = (const u8*)d_in[6];
    const u8* boot_mask  = (const u8*)d_in[7];
    float* out = (float*)d_out;
    float* ws  = (float*)d_ws;

    long ws_floats = (long)(ws_size / 4);
    long per_e = (long)F * Q / 2 + (long)B * Q;        // bf-frag + sim per ensemble
    int chunk = (int)((ws_floats - (long)W_BF) / per_e);
    if (chunk > 16) chunk = 16;
    if (chunk < 1) chunk = 1;

    u16* af = (u16*)(ws + W_AF);
    u16* bf = (u16*)(ws + W_BF);
    float* sim = ws + W_BF + (size_t)chunk * (F * Q / 2);

    // zero scores_acc + cnt_acc + unc_acc (contiguous 2101248 floats)
    k_zero<<<2101248 / 256, 256, 0, stream>>>(ws + W_SCORES);
    k_afrag<<<E * B, 128, 0, stream>>>(teacher, mask_t, af);
    k_invn<<<dim3(E, Q / 256), 256, 0, stream>>>(neg, mask_n, ws + W_INVN);
    k_logits<<<B, 256, 0, stream>>>(query, key, neg, out);
    k_rowstats<<<B, 256, 0, stream>>>(out, ws + W_MOCO, ws + W_NLSE);

    for (int e0 = 0; e0 < E; e0 += chunk) {
        int ecnt = (E - e0 < chunk) ? (E - e0) : chunk;
        k_bfrag<<<dim3(256, ecnt), 256, 0, stream>>>(neg, mask_n, ws + W_INVN, bf, e0);
        k_mfma<<<dim3(Q / 256, B / 16, ecnt), 256, 0, stream>>>(af, bf, sim, e0);
        k_entropy<<<dim3(Q / 64, ecnt), 256, 0, stream>>>(sim, boot_mask, ws + W_UNC, e0);
        k_rowmax<<<dim3(B, ecnt), 256, 0, stream>>>(sim, score_mask,
                                                    ws + W_MROW, ws + W_SROW, e0);
        k_accum<<<(B * Q) / 256, 256, 0, stream>>>(sim, score_mask, ws + W_MROW,
                                                   ws + W_SROW, ws + W_SCORES,
                                                   ws + W_CNT, e0, ecnt);
    }

    k_finscores<<<(B * Q) / 256, 256, 0, stream>>>(ws + W_SCORES, ws + W_CNT);
    k_median<<<1, 1024, 0, stream>>>(ws + W_UNC, ws + W_UB);
    k_select<<<dim3(B, 2), 256, 0, stream>>>(out, ws + W_SCORES, ws + W_UNC, ws + W_UB,
                                             ws + W_NLSE, ws + W_EASY, ws + W_HARD);
    k_scalars<<<1, 256, 0, stream>>>(ws + W_MOCO, ws + W_EASY, ws + W_HARD, out);
}